// Round 3
// baseline (1353.333 us; speedup 1.0000x reference)
//
#include <hip/hip_runtime.h>

// ---------------------------------------------------------------------------
// QuantizedAttention: x[B,S,D] -> QKV proj (int8-quant wts) -> RMSNorm -> RoPE
//   -> causal GQA attention -> O proj.  B=2 S=2048 D=2048 H=16 KVH=8 HD=128.
// R3: attn v3 — bounded-score softmax (no running max), kv-split across waves
// (no per-iter cross-wave traffic), S^T MFMA layout (P regs feed PV directly),
// global_load_lds + XOR-swizzled LDS + double-buffered prefetch.
// ---------------------------------------------------------------------------

typedef __attribute__((ext_vector_type(4))) float floatx4;
typedef __attribute__((ext_vector_type(8))) short short8v;
typedef __attribute__((ext_vector_type(4))) short short4v;
typedef __attribute__((ext_vector_type(8))) unsigned short ushort8v;
typedef __attribute__((ext_vector_type(4))) unsigned short ushort4v;

#define DEVINL __device__ __forceinline__

constexpr int cB = 2, cS = 2048, cD = 2048, cH = 16, cKVH = 8, cHD = 128;
constexpr int cM = cB * cS;
constexpr int cNqkv = (cH + 2 * cKVH) * cHD;
constexpr float cEPS = 1e-6f;
constexpr float cSCALE = 0.08838834764831845f;   // 1/sqrt(HD)

DEVINL unsigned short f2bf(float f) {
  unsigned u = __float_as_uint(f);
  unsigned r = ((u >> 16) & 1u) + 0x7FFFu;
  return (unsigned short)((u + r) >> 16);
}
DEVINL float bf2f(unsigned short h) { return __uint_as_float(((unsigned)h) << 16); }

DEVINL floatx4 mfma_bf16(short8v a, short8v b, floatx4 c) {
  return __builtin_amdgcn_mfma_f32_16x16x32_bf16(a, b, c, 0, 0, 0);
}

// K=16 bf16 MFMA for PV (A = P regs in S^T C-layout, k = q*4+j).
DEVINL floatx4 mfma_pv(short4v a, short4v b, floatx4 c) {
#if __has_builtin(__builtin_amdgcn_mfma_f32_16x16x16bf16_1k)
  return __builtin_amdgcn_mfma_f32_16x16x16bf16_1k(a, b, c, 0, 0, 0);
#else
  // zero-padded K32 fallback: A zero in k=q*8+4..7 kills those terms.
  short8v a8 = {a[0], a[1], a[2], a[3], (short)0, (short)0, (short)0, (short)0};
  short8v b8 = {b[0], b[1], b[2], b[3], (short)0, (short)0, (short)0, (short)0};
  return __builtin_amdgcn_mfma_f32_16x16x32_bf16(a8, b8, c, 0, 0, 0);
#endif
}

DEVINL void gl_lds16(const void* g, void* l) {
  __builtin_amdgcn_global_load_lds(
      (const __attribute__((address_space(1))) void*)g,
      (__attribute__((address_space(3))) void*)l, 16, 0, 0);
}

// --------------------------- dtype detection -------------------------------
__global__ void detect_dtype(const unsigned* __restrict__ x, int* __restrict__ flag) {
  __shared__ int cnt;
  if (threadIdx.x == 0) cnt = 0;
  __syncthreads();
  int c = 0;
  for (int i = threadIdx.x; i < 4096; i += 256) {
    unsigned e = (x[i] >> 7) & 0xFFu;
    c += (e >= 100u && e <= 142u) ? 1 : 0;
  }
  atomicAdd(&cnt, c);
  __syncthreads();
  if (threadIdx.x == 0) *flag = (cnt > 2457) ? 1 : 0;  // 1 = host is bf16
}

// --------------------------- conversions -----------------------------------
__global__ void conv_x(const void* __restrict__ src, unsigned short* __restrict__ dst,
                       int n, const int* __restrict__ flag) {
  int i = (blockIdx.x * 256 + threadIdx.x) * 8;
  if (i >= n) return;
  if (*flag) {
    *(ushort8v*)(dst + i) = *(const ushort8v*)((const unsigned short*)src + i);
  } else {
    const float* s = (const float*)src;
    ushort8v o;
#pragma unroll
    for (int j = 0; j < 8; j++) o[j] = f2bf(s[i + j]);
    *(ushort8v*)(dst + i) = o;
  }
}

__global__ void conv_f32(const void* __restrict__ src, float* __restrict__ dst,
                         int n, const int* __restrict__ flag) {
  int i = blockIdx.x * 256 + threadIdx.x;
  if (i >= n) return;
  dst[i] = (*flag) ? bf2f(((const unsigned short*)src)[i]) : ((const float*)src)[i];
}

__global__ void conv_w(const int* __restrict__ w, unsigned short* __restrict__ dst, int n) {
  int i = (blockIdx.x * 256 + threadIdx.x) * 4;
  if (i >= n) return;
  int4 v = *(const int4*)(w + i);
  ushort4v o;
  o[0] = f2bf((float)v.x); o[1] = f2bf((float)v.y);
  o[2] = f2bf((float)v.z); o[3] = f2bf((float)v.w);
  *(ushort4v*)(dst + i) = o;
}

__global__ void out_conv(const float* __restrict__ of, void* __restrict__ dout,
                         int n, const int* __restrict__ flag) {
  int i = blockIdx.x * 256 + threadIdx.x;
  if (i >= n) return;
  float v = of[i];
  if (*flag) ((unsigned short*)dout)[i] = f2bf(v);
  else       ((float*)dout)[i] = v;
}

// --------------------------- bf16 GEMM (B^T) -------------------------------
__global__ __launch_bounds__(256) void gemm_bt(
    const unsigned short* __restrict__ A, const unsigned short* __restrict__ Bw,
    const float* __restrict__ colscale, float* __restrict__ C,
    int M, int N, int K) {
  constexpr int BK = 64, LDT = BK + 8;
  __shared__ unsigned short As[128 * LDT];
  __shared__ unsigned short Bs[128 * LDT];
  const int tid = threadIdx.x;
  const int lane = tid & 63, wave = tid >> 6;
  const int q = lane >> 4, l16 = lane & 15;
  const int m0 = blockIdx.y * 128, n0 = blockIdx.x * 128;
  const int wm = (wave & 1) * 64, wn = (wave >> 1) * 64;

  floatx4 acc[4][4] = {};

  const int srow = tid >> 1, scol = (tid & 1) * 32;
  const unsigned short* Ag = A + (size_t)(m0 + srow) * K + scol;
  const unsigned short* Bg = Bw + (size_t)(n0 + srow) * K + scol;
  unsigned short* Asw = As + srow * LDT + scol;
  unsigned short* Bsw = Bs + srow * LDT + scol;

  for (int k0 = 0; k0 < K; k0 += BK) {
    ushort8v a0 = *(const ushort8v*)(Ag + k0 + 0);
    ushort8v a1 = *(const ushort8v*)(Ag + k0 + 8);
    ushort8v a2 = *(const ushort8v*)(Ag + k0 + 16);
    ushort8v a3 = *(const ushort8v*)(Ag + k0 + 24);
    ushort8v b0 = *(const ushort8v*)(Bg + k0 + 0);
    ushort8v b1 = *(const ushort8v*)(Bg + k0 + 8);
    ushort8v b2 = *(const ushort8v*)(Bg + k0 + 16);
    ushort8v b3 = *(const ushort8v*)(Bg + k0 + 24);
    __syncthreads();
    *(ushort8v*)(Asw + 0)  = a0;
    *(ushort8v*)(Asw + 8)  = a1;
    *(ushort8v*)(Asw + 16) = a2;
    *(ushort8v*)(Asw + 24) = a3;
    *(ushort8v*)(Bsw + 0)  = b0;
    *(ushort8v*)(Bsw + 8)  = b1;
    *(ushort8v*)(Bsw + 16) = b2;
    *(ushort8v*)(Bsw + 24) = b3;
    __syncthreads();
#pragma unroll
    for (int kk = 0; kk < BK; kk += 32) {
      short8v af[4], bf[4];
#pragma unroll
      for (int mt = 0; mt < 4; mt++)
        af[mt] = *(const short8v*)(As + (wm + mt * 16 + l16) * LDT + kk + q * 8);
#pragma unroll
      for (int nt = 0; nt < 4; nt++)
        bf[nt] = *(const short8v*)(Bs + (wn + nt * 16 + l16) * LDT + kk + q * 8);
#pragma unroll
      for (int mt = 0; mt < 4; mt++)
#pragma unroll
        for (int nt = 0; nt < 4; nt++)
          acc[mt][nt] = mfma_bf16(af[mt], bf[nt], acc[mt][nt]);
    }
  }
#pragma unroll
  for (int mt = 0; mt < 4; mt++) {
    int r0 = m0 + wm + mt * 16 + q * 4;
#pragma unroll
    for (int nt = 0; nt < 4; nt++) {
      int cn = n0 + wn + nt * 16 + l16;
      float sc = colscale[cn];
#pragma unroll
      for (int rg = 0; rg < 4; rg++)
        C[(size_t)(r0 + rg) * N + cn] = acc[mt][nt][rg] * sc;
    }
  }
}

// --------------------------- RMSNorm + RoPE --------------------------------
__global__ __launch_bounds__(64) void rmsrope(
    const float* __restrict__ QKV, const float* __restrict__ cosc,
    const float* __restrict__ sinc, const float* __restrict__ nw,
    unsigned short* __restrict__ Qb, unsigned short* __restrict__ Kb) {
  const int t = threadIdx.x;
  const int row = blockIdx.x;
  const int hidx = blockIdx.y;
  const int sidx = row & (cS - 1);
  const int bi = row >> 11;
  const bool isq = hidx < cH;
  const int col = isq ? hidx * cHD : cH * cHD + (hidx - cH) * cHD;
  const float* src = QKV + (size_t)row * cNqkv + col;
  float x1 = src[t], x2 = src[t + 64];
  float ss = x1 * x1 + x2 * x2;
  ss += __shfl_xor(ss, 1);  ss += __shfl_xor(ss, 2);  ss += __shfl_xor(ss, 4);
  ss += __shfl_xor(ss, 8);  ss += __shfl_xor(ss, 16); ss += __shfl_xor(ss, 32);
  float inv = rsqrtf(ss * (1.0f / cHD) + cEPS);
  const float* w = nw + (isq ? 0 : cHD);
  float n1 = x1 * inv * w[t], n2 = x2 * inv * w[t + 64];
  float c1 = cosc[sidx * cHD + t], c2 = cosc[sidx * cHD + t + 64];
  float s1 = sinc[sidx * cHD + t], s2 = sinc[sidx * cHD + t + 64];
  float o1 = n1 * c1 - n2 * s1;
  float o2 = n2 * c2 + n1 * s2;
  unsigned short* dst = isq
      ? (Qb + ((size_t)(bi * cH + hidx) * cS + sidx) * cHD)
      : (Kb + ((size_t)(bi * cKVH + (hidx - cH)) * cS + sidx) * cHD);
  dst[t] = f2bf(o1);
  dst[t + 64] = f2bf(o2);
}

// --------------------------- V transpose -----------------------------------
__global__ __launch_bounds__(256) void vtrans(const float* __restrict__ QKV,
                                              unsigned short* __restrict__ Vt) {
  __shared__ unsigned short tile[64][72];
  const int t = threadIdx.x;
  const int s0 = blockIdx.x * 64, d0 = blockIdx.y * 64, bi = blockIdx.z;
  {
    const int rr = t >> 2, c0 = (t & 3) * 16;
    const float* src = QKV + (size_t)(bi * cS + s0 + rr) * cNqkv
                       + (cH * cHD + cKVH * cHD) + d0 + c0;
#pragma unroll
    for (int j = 0; j < 16; j += 4) {
      float4 v = *(const float4*)(src + j);
      tile[rr][c0 + j + 0] = f2bf(v.x);
      tile[rr][c0 + j + 1] = f2bf(v.y);
      tile[rr][c0 + j + 2] = f2bf(v.z);
      tile[rr][c0 + j + 3] = f2bf(v.w);
    }
  }
  __syncthreads();
  {
    const int dd = t >> 2, sc0 = (t & 3) * 16;
    const int dglob = d0 + dd;
    const int kh = dglob >> 7, dh = dglob & 127;
    unsigned short* dst = Vt + ((size_t)(bi * cKVH + kh) * cHD + dh) * cS + s0 + sc0;
    ushort8v o0, o1;
#pragma unroll
    for (int j = 0; j < 8; j++) { o0[j] = tile[sc0 + j][dd]; o1[j] = tile[sc0 + 8 + j][dd]; }
    *(ushort8v*)dst = o0;
    *(ushort8v*)(dst + 8) = o1;
  }
}

// --------------------------- flash attention (v3) --------------------------
// Block = 64 q-rows of one (b,h); 4 waves. Wave w owns kv slice [w*16,w*16+16)
// of each 64-kv window. Bounded scores (RMSNormed q,k => |s|/sqrt(HD) <=
// sqrt(128)) => no running max: P = exp(s*scale), l and O are plain sums =>
// zero cross-wave traffic in the loop; one LDS O/l reduction per block.
// S^T = K*Q^T so P's C-layout (kv=q*4+rg) IS the K=16 PV A-fragment.
// K/V staged via global_load_lds into XOR-swizzled LDS, double-buffered:
// DMA(win+1) issued right after the single per-iter barrier, covered by
// compute(win), drained at the next barrier.
__global__ __launch_bounds__(256, 2) void attn(
    const unsigned short* __restrict__ Qb, const unsigned short* __restrict__ Kb,
    const unsigned short* __restrict__ Vt, unsigned short* __restrict__ AO) {
  constexpr int OLD = 68;                 // O^T reduce stride (fp32, +4 pad)
  __shared__ float4 smem4[4096];          // 64 KiB: 2 x (Ks 16K + Vs 16K); aliased by OT/Lr
  unsigned short* SM = (unsigned short*)smem4;
  float* OT = (float*)smem4;              // [128][68] fp32 (34816 B)
  float* Lr = (float*)smem4 + 128 * OLD;  // [4][64] fp32

  const int tid = threadIdx.x;
  const int lane = tid & 63, wv = tid >> 6;
  const int q = lane >> 4, l16 = lane & 15;
  const int bi = blockIdx.z, h = blockIdx.y;
  const int kh = h >> 1;                  // GQA: rep = 2
  const int qt = (int)gridDim.x - 1 - (int)blockIdx.x;  // LPT: heavy tiles first
  const int q0 = qt * 64;

  const unsigned short* Qbase = Qb + ((size_t)(bi * cH + h) * cS + q0) * cHD;
  const unsigned short* Kbase = Kb + ((size_t)(bi * cKVH + kh) * cS) * cHD;
  const unsigned short* Vbase = Vt + ((size_t)(bi * cKVH + kh) * cHD) * cS;

  // ---- Q B-fragments, all 64 q-rows, held in registers (64 VGPR) ----
  short8v qf[4][4];
#pragma unroll
  for (int nt = 0; nt < 4; nt++)
#pragma unroll
    for (int c = 0; c < 4; c++)
      qf[nt][c] = *(const short8v*)(Qbase + (size_t)(nt * 16 + l16) * cHD + c * 32 + q * 8);

  floatx4 oacc[4][8] = {};   // [q m-tile][d tile]; rg -> row q*4+rg, col l16
  float lp[4] = {0.f, 0.f, 0.f, 0.f};

  // ---- staging source offsets (XOR-swizzled, 16B units) ----
  // K tile [64 kv][128 hd]: 1024 units; slot s -> row r=s>>4, u_lds=s&15,
  // content = global unit u_lds^(r&15). V tile [128 d][64 kv]: slot s ->
  // d=s>>3, u_lds=s&7, content = global unit u_lds^(d&7).
  int koff[4], voff[4];
#pragma unroll
  for (int i = 0; i < 4; i++) {
    int s = (wv * 4 + i) * 64 + lane;
    int r = s >> 4, u = (s & 15) ^ (r & 15);
    koff[i] = r * cHD + u * 8;
    int d = s >> 3, uv = (s & 7) ^ (d & 7);
    voff[i] = d * cS + uv * 8;
  }
  const int kvs = wv * 16;   // this wave's kv slice offset within a window

  auto stage = [&](int win) {
    const int buf = (win & 1) * 16384;             // ushort offset (32 KiB)
    const int kv0 = win * 64;
    unsigned short* Kdst = SM + buf + (wv * 4) * 512;
    unsigned short* Vdst = SM + buf + 8192 + (wv * 4) * 512;
#pragma unroll
    for (int i = 0; i < 4; i++)
      gl_lds16(Kbase + (size_t)kv0 * cHD + koff[i], Kdst + i * 512);
#pragma unroll
    for (int i = 0; i < 4; i++)
      gl_lds16(Vbase + (size_t)kv0 + voff[i], Vdst + i * 512);
  };

  stage(0);
  for (int win = 0; win <= qt; win++) {
    __syncthreads();                 // drains DMA(win); prev-buf reads done
    if (win < qt) stage(win + 1);    // in flight during compute(win)
    const unsigned short* Ks = SM + (win & 1) * 16384;
    const unsigned short* Vs = Ks + 8192;
    const int kv0 = win * 64;

    // ---- QK^T -> S^T[16 kv][64 q] for this wave's slice ----
    floatx4 sres[4] = {};
#pragma unroll
    for (int c = 0; c < 4; c++) {
      short8v kf = *(const short8v*)(Ks + (kvs + l16) * 128 + (((c * 4 + q) ^ l16) * 8));
#pragma unroll
      for (int nt = 0; nt < 4; nt++)
        sres[nt] = mfma_bf16(kf, qf[nt][c], sres[nt]);
    }

    // ---- bounded-score softmax numerator (no max) ----
    const bool lastwin = (kv0 == q0);
    short4v pa[4];
#pragma unroll
    for (int nt = 0; nt < 4; nt++) {
#pragma unroll
      for (int rg = 0; rg < 4; rg++) {
        float e = __expf(sres[nt][rg] * cSCALE);
        if (lastwin)
          e = (kvs + q * 4 + rg <= nt * 16 + l16) ? e : 0.f;
        sres[nt][rg] = e;
        lp[nt] += e;
        pa[nt][rg] = (short)f2bf(e);
      }
    }

    // ---- PV: O[64 q][128 d] += P^T-slice * V-slice (K=16) ----
    short4v vb[8];
#pragma unroll
    for (int db = 0; db < 8; db++)
      vb[db] = *(const short4v*)(Vs + (db * 16 + l16) * 64 +
                                 (((wv * 2 + (q >> 1)) ^ (l16 & 7)) * 8 + (q & 1) * 4));
#pragma unroll
    for (int mt = 0; mt < 4; mt++)
#pragma unroll
      for (int db = 0; db < 8; db++)
        oacc[mt][db] = mfma_pv(pa[mt], vb[db], oacc[mt][db]);
  }

  // ---- cross-quad l reduction (lanes sharing (nt,l16)) ----
  float lq[4];
#pragma unroll
  for (int nt = 0; nt < 4; nt++) {
    float l = lp[nt];
    l += __shfl_xor(l, 16);
    l += __shfl_xor(l, 32);
    lq[nt] = l;
  }

  // ---- cross-wave O/l reduction through LDS (rotating d-chunks) ----
  __syncthreads();                       // loop LDS reads done; safe to alias
  if (q == 0) {
#pragma unroll
    for (int nt = 0; nt < 4; nt++) Lr[wv * 64 + nt * 16 + l16] = lq[nt];
  }
#pragma unroll
  for (int dbi = 0; dbi < 2; dbi++) {    // round 0: write own chunk wv
    int db = wv * 2 + dbi;
#pragma unroll
    for (int mt = 0; mt < 4; mt++)
      *(floatx4*)&OT[(db * 16 + l16) * OLD + mt * 16 + q * 4] = oacc[mt][db];
  }
  floatx4 ofin[4][2];
#pragma unroll
  for (int r = 1; r < 4; r++) {
    __syncthreads();
    int c = (wv + r) & 3;
#pragma unroll
    for (int dbi = 0; dbi < 2; dbi++) {
      int db = c * 2 + dbi;
#pragma unroll
      for (int mt = 0; mt < 4; mt++) {
        floatx4* ad = (floatx4*)&OT[(db * 16 + l16) * OLD + mt * 16 + q * 4];
        floatx4 v = *ad + oacc[mt][db];
        if (r < 3) *ad = v;
        else       ofin[mt][dbi] = v;    // final sum for chunk (wv+3)&3
      }
    }
  }
  // ---- finalize: 1/l and store (Lr complete since round-0 + barriers) ----
  floatx4 li[4];
#pragma unroll
  for (int mt = 0; mt < 4; mt++) {
    floatx4 s = *(floatx4*)&Lr[0 * 64 + mt * 16 + q * 4];
    s += *(floatx4*)&Lr[1 * 64 + mt * 16 + q * 4];
    s += *(floatx4*)&Lr[2 * 64 + mt * 16 + q * 4];
    s += *(floatx4*)&Lr[3 * 64 + mt * 16 + q * 4];
#pragma unroll
    for (int rg = 0; rg < 4; rg++) li[mt][rg] = 1.0f / s[rg];
  }
  const int cfin = (wv + 3) & 3;
#pragma unroll
  for (int mt = 0; mt < 4; mt++) {
#pragma unroll
    for (int rg = 0; rg < 4; rg++) {
      int row = q0 + mt * 16 + q * 4 + rg;
      unsigned short* dst = AO + (size_t)(bi * cS + row) * (cH * cHD) + h * cHD;
#pragma unroll
      for (int dbi = 0; dbi < 2; dbi++)
        dst[(cfin * 2 + dbi) * 16 + l16] = f2bf(ofin[mt][dbi][rg] * li[mt][rg]);
    }
  }
}

// --------------------------- launch ----------------------------------------
extern "C" void kernel_launch(void* const* d_in, const int* in_sizes, int n_in,
                              void* d_out, int out_size, void* d_ws, size_t ws_size,
                              hipStream_t stream) {
  (void)in_sizes; (void)n_in; (void)out_size; (void)ws_size;
  char* ws = (char*)d_ws;
  size_t off = 0;
  auto alloc = [&](size_t bytes) -> char* {
    char* p = ws + off;
    off += (bytes + 255) & ~((size_t)255);
    return p;
  };
  int* flag            = (int*)alloc(256);
  float* cosf_         = (float*)alloc((size_t)cS * cHD * 4);
  float* sinf_         = (float*)alloc((size_t)cS * cHD * 4);
  float* nw            = (float*)alloc(256 * 4);
  float* scat          = (float*)alloc(4096 * 4);
  float* so            = (float*)alloc(2048 * 4);
  unsigned short* xb   = (unsigned short*)alloc((size_t)cM * cD * 2);
  unsigned short* wcat = (unsigned short*)alloc((size_t)cNqkv * cD * 2);
  unsigned short* wob  = (unsigned short*)alloc((size_t)cD * cH * cHD * 2);
  unsigned short* Qb   = (unsigned short*)alloc((size_t)cB * cH * cS * cHD * 2);
  unsigned short* Kb   = (unsigned short*)alloc((size_t)cB * cKVH * cS * cHD * 2);
  unsigned short* Vt   = (unsigned short*)alloc((size_t)cB * cKVH * cHD * cS * 2);
  char* big            = alloc((size_t)cM * cNqkv * 4);
  float* qkvf          = (float*)big;
  unsigned short* AO   = (unsigned short*)big;
  float* of            = (float*)(big + (size_t)cM * cNqkv * 2);

  detect_dtype<<<1, 256, 0, stream>>>((const unsigned*)d_in[0], flag);

  conv_x<<<(cM * cD / 8 + 255) / 256, 256, 0, stream>>>(d_in[0], xb, cM * cD, flag);
  conv_f32<<<(cS * cHD + 255) / 256, 256, 0, stream>>>(d_in[11], cosf_, cS * cHD, flag);
  conv_f32<<<(cS * cHD + 255) / 256, 256, 0, stream>>>(d_in[12], sinf_, cS * cHD, flag);
  conv_f32<<<1, 256, 0, stream>>>(d_in[9], nw, cHD, flag);
  conv_f32<<<1, 256, 0, stream>>>(d_in[10], nw + cHD, cHD, flag);
  conv_f32<<<8, 256, 0, stream>>>(d_in[2], scat, 2048, flag);
  conv_f32<<<4, 256, 0, stream>>>(d_in[4], scat + 2048, 1024, flag);
  conv_f32<<<4, 256, 0, stream>>>(d_in[6], scat + 3072, 1024, flag);
  conv_f32<<<8, 256, 0, stream>>>(d_in[8], so, 2048, flag);
  conv_w<<<(2048 * 2048 / 4 + 255) / 256, 256, 0, stream>>>((const int*)d_in[1], wcat, 2048 * 2048);
  conv_w<<<(1024 * 2048 / 4 + 255) / 256, 256, 0, stream>>>((const int*)d_in[3], wcat + (size_t)2048 * 2048, 1024 * 2048);
  conv_w<<<(1024 * 2048 / 4 + 255) / 256, 256, 0, stream>>>((const int*)d_in[5], wcat + (size_t)3072 * 2048, 1024 * 2048);
  conv_w<<<(2048 * 2048 / 4 + 255) / 256, 256, 0, stream>>>((const int*)d_in[7], wob, 2048 * 2048);

  gemm_bt<<<dim3(cNqkv / 128, cM / 128), 256, 0, stream>>>(xb, wcat, scat, qkvf, cM, cNqkv, cD);
  rmsrope<<<dim3(cM, cH + cKVH), 64, 0, stream>>>(qkvf, cosf_, sinf_, nw, Qb, Kb);
  vtrans<<<dim3(cS / 64, cKVH * cHD / 64, cB), 256, 0, stream>>>(qkvf, Vt);
  attn<<<dim3(cS / 64, cH, cB), 256, 0, stream>>>(Qb, Kb, Vt, AO);
  gemm_bt<<<dim3(cD / 128, cM / 128), 256, 0, stream>>>(AO, wob, so, of, cM, cD, cH * cHD);
  out_conv<<<(cM * cD + 255) / 256, 256, 0, stream>>>(of, d_out, cM * cD, flag);
}

// Round 4
// 435.924 us; speedup vs baseline: 3.1045x; 3.1045x over previous
//
#include <hip/hip_runtime.h>

// ---------------------------------------------------------------------------
// QuantizedAttention: x[B,S,D] -> QKV proj (int8-quant wts) -> RMSNorm -> RoPE
//   -> causal GQA attention -> O proj.  B=2 S=2048 D=2048 H=16 KVH=8 HD=128.
// R4: attn v4 — q-split waves (16 q-rows/wave, ~110 VGPR, no spill) keeping
// R3's validated machinery: no-max bounded-score softmax, S^T layout (P regs
// feed K16 PV directly), global_load_lds + XOR swizzle + double buffer.
// gemm_bt v2 — m97-style global_load_lds staging, XOR-swizzled LDS.
// ---------------------------------------------------------------------------

typedef __attribute__((ext_vector_type(4))) float floatx4;
typedef __attribute__((ext_vector_type(8))) short short8v;
typedef __attribute__((ext_vector_type(4))) short short4v;
typedef __attribute__((ext_vector_type(8))) unsigned short ushort8v;
typedef __attribute__((ext_vector_type(4))) unsigned short ushort4v;

#define DEVINL __device__ __forceinline__

constexpr int cB = 2, cS = 2048, cD = 2048, cH = 16, cKVH = 8, cHD = 128;
constexpr int cM = cB * cS;
constexpr int cNqkv = (cH + 2 * cKVH) * cHD;
constexpr float cEPS = 1e-6f;
constexpr float cSCALE = 0.08838834764831845f;   // 1/sqrt(HD)

DEVINL unsigned short f2bf(float f) {
  unsigned u = __float_as_uint(f);
  unsigned r = ((u >> 16) & 1u) + 0x7FFFu;
  return (unsigned short)((u + r) >> 16);
}
DEVINL float bf2f(unsigned short h) { return __uint_as_float(((unsigned)h) << 16); }

DEVINL floatx4 mfma_bf16(short8v a, short8v b, floatx4 c) {
  return __builtin_amdgcn_mfma_f32_16x16x32_bf16(a, b, c, 0, 0, 0);
}

// K=16 bf16 MFMA for PV (A = P regs in S^T C-layout, k = q*4+rg).
DEVINL floatx4 mfma_pv(short4v a, short4v b, floatx4 c) {
#if __has_builtin(__builtin_amdgcn_mfma_f32_16x16x16bf16_1k)
  return __builtin_amdgcn_mfma_f32_16x16x16bf16_1k(a, b, c, 0, 0, 0);
#else
  short8v a8 = {a[0], a[1], a[2], a[3], (short)0, (short)0, (short)0, (short)0};
  short8v b8 = {b[0], b[1], b[2], b[3], (short)0, (short)0, (short)0, (short)0};
  return __builtin_amdgcn_mfma_f32_16x16x32_bf16(a8, b8, c, 0, 0, 0);
#endif
}

DEVINL void gl_lds16(const void* g, void* l) {
  __builtin_amdgcn_global_load_lds(
      (const __attribute__((address_space(1))) void*)g,
      (__attribute__((address_space(3))) void*)l, 16, 0, 0);
}

// --------------------------- dtype detection -------------------------------
__global__ void detect_dtype(const unsigned* __restrict__ x, int* __restrict__ flag) {
  __shared__ int cnt;
  if (threadIdx.x == 0) cnt = 0;
  __syncthreads();
  int c = 0;
  for (int i = threadIdx.x; i < 4096; i += 256) {
    unsigned e = (x[i] >> 7) & 0xFFu;
    c += (e >= 100u && e <= 142u) ? 1 : 0;
  }
  atomicAdd(&cnt, c);
  __syncthreads();
  if (threadIdx.x == 0) *flag = (cnt > 2457) ? 1 : 0;  // 1 = host is bf16
}

// --------------------------- conversions -----------------------------------
__global__ void conv_x(const void* __restrict__ src, unsigned short* __restrict__ dst,
                       int n, const int* __restrict__ flag) {
  int i = (blockIdx.x * 256 + threadIdx.x) * 8;
  if (i >= n) return;
  if (*flag) {
    *(ushort8v*)(dst + i) = *(const ushort8v*)((const unsigned short*)src + i);
  } else {
    const float* s = (const float*)src;
    ushort8v o;
#pragma unroll
    for (int j = 0; j < 8; j++) o[j] = f2bf(s[i + j]);
    *(ushort8v*)(dst + i) = o;
  }
}

__global__ void conv_f32(const void* __restrict__ src, float* __restrict__ dst,
                         int n, const int* __restrict__ flag) {
  int i = blockIdx.x * 256 + threadIdx.x;
  if (i >= n) return;
  dst[i] = (*flag) ? bf2f(((const unsigned short*)src)[i]) : ((const float*)src)[i];
}

__global__ void conv_w(const int* __restrict__ w, unsigned short* __restrict__ dst, int n) {
  int i = (blockIdx.x * 256 + threadIdx.x) * 4;
  if (i >= n) return;
  int4 v = *(const int4*)(w + i);
  ushort4v o;
  o[0] = f2bf((float)v.x); o[1] = f2bf((float)v.y);
  o[2] = f2bf((float)v.z); o[3] = f2bf((float)v.w);
  *(ushort4v*)(dst + i) = o;
}

__global__ void out_conv(const float* __restrict__ of, void* __restrict__ dout,
                         int n, const int* __restrict__ flag) {
  int i = blockIdx.x * 256 + threadIdx.x;
  if (i >= n) return;
  float v = of[i];
  if (*flag) ((unsigned short*)dout)[i] = f2bf(v);
  else       ((float*)dout)[i] = v;
}

// --------------------------- bf16 GEMM (B^T), m97-style --------------------
// C[M,N] = (A[M,K] @ B[N,K]^T) * colscale[N].  128x128x64 tiles, 4 waves,
// global_load_lds width-16 staging into XOR-swizzled LDS (no padding; 16B
// unit u of row r stored at slot u^(r&7); fragment reads de-swizzle with
// l16&7 so all LDS reads are <=2-way bank aliasing).
__global__ __launch_bounds__(256) void gemm_bt(
    const unsigned short* __restrict__ A, const unsigned short* __restrict__ Bw,
    const float* __restrict__ colscale, float* __restrict__ C,
    int M, int N, int K) {
  __shared__ unsigned short As[128 * 64];   // 16 KiB
  __shared__ unsigned short Bs[128 * 64];   // 16 KiB
  const int tid = threadIdx.x;
  const int lane = tid & 63, wave = tid >> 6;
  const int q = lane >> 4, l16 = lane & 15;
  const int m0 = blockIdx.y * 128, n0 = blockIdx.x * 128;
  const int wm = (wave & 1) * 64, wn = (wave >> 1) * 64;

  floatx4 acc[4][4] = {};

  // staging: slot s = (wave*4+i)*64 + lane; row r=s>>3, lds unit s&7 holds
  // global unit (s&7)^(r&7).
  int goff[4];
#pragma unroll
  for (int i = 0; i < 4; i++) {
    int s = (wave * 4 + i) * 64 + lane;
    int r = s >> 3, u = (s & 7) ^ (r & 7);
    goff[i] = r * K + u * 8;
  }
  const unsigned short* Ag = A + (size_t)m0 * K;
  const unsigned short* Bg = Bw + (size_t)n0 * K;

  for (int k0 = 0; k0 < K; k0 += 64) {
    __syncthreads();                        // prior compute done with LDS
#pragma unroll
    for (int i = 0; i < 4; i++)
      gl_lds16(Ag + k0 + goff[i], (char*)As + (wave * 4 + i) * 1024);
#pragma unroll
    for (int i = 0; i < 4; i++)
      gl_lds16(Bg + k0 + goff[i], (char*)Bs + (wave * 4 + i) * 1024);
    __syncthreads();                        // drains this wave's DMA (vmcnt)
#pragma unroll
    for (int kk = 0; kk < 2; kk++) {
      short8v af[4], bf[4];
#pragma unroll
      for (int mt = 0; mt < 4; mt++) {
        int row = wm + mt * 16 + l16;
        af[mt] = *(const short8v*)(As + row * 64 + (((kk * 4 + q) ^ (l16 & 7)) * 8));
      }
#pragma unroll
      for (int nt = 0; nt < 4; nt++) {
        int row = wn + nt * 16 + l16;
        bf[nt] = *(const short8v*)(Bs + row * 64 + (((kk * 4 + q) ^ (l16 & 7)) * 8));
      }
#pragma unroll
      for (int mt = 0; mt < 4; mt++)
#pragma unroll
        for (int nt = 0; nt < 4; nt++)
          acc[mt][nt] = mfma_bf16(af[mt], bf[nt], acc[mt][nt]);
    }
  }
#pragma unroll
  for (int mt = 0; mt < 4; mt++) {
    int r0 = m0 + wm + mt * 16 + q * 4;
#pragma unroll
    for (int nt = 0; nt < 4; nt++) {
      int cn = n0 + wn + nt * 16 + l16;
      float sc = colscale[cn];
#pragma unroll
      for (int rg = 0; rg < 4; rg++)
        C[(size_t)(r0 + rg) * N + cn] = acc[mt][nt][rg] * sc;
    }
  }
}

// --------------------------- RMSNorm + RoPE --------------------------------
__global__ __launch_bounds__(64) void rmsrope(
    const float* __restrict__ QKV, const float* __restrict__ cosc,
    const float* __restrict__ sinc, const float* __restrict__ nw,
    unsigned short* __restrict__ Qb, unsigned short* __restrict__ Kb) {
  const int t = threadIdx.x;
  const int row = blockIdx.x;
  const int hidx = blockIdx.y;
  const int sidx = row & (cS - 1);
  const int bi = row >> 11;
  const bool isq = hidx < cH;
  const int col = isq ? hidx * cHD : cH * cHD + (hidx - cH) * cHD;
  const float* src = QKV + (size_t)row * cNqkv + col;
  float x1 = src[t], x2 = src[t + 64];
  float ss = x1 * x1 + x2 * x2;
  ss += __shfl_xor(ss, 1);  ss += __shfl_xor(ss, 2);  ss += __shfl_xor(ss, 4);
  ss += __shfl_xor(ss, 8);  ss += __shfl_xor(ss, 16); ss += __shfl_xor(ss, 32);
  float inv = rsqrtf(ss * (1.0f / cHD) + cEPS);
  const float* w = nw + (isq ? 0 : cHD);
  float n1 = x1 * inv * w[t], n2 = x2 * inv * w[t + 64];
  float c1 = cosc[sidx * cHD + t], c2 = cosc[sidx * cHD + t + 64];
  float s1 = sinc[sidx * cHD + t], s2 = sinc[sidx * cHD + t + 64];
  float o1 = n1 * c1 - n2 * s1;
  float o2 = n2 * c2 + n1 * s2;
  unsigned short* dst = isq
      ? (Qb + ((size_t)(bi * cH + hidx) * cS + sidx) * cHD)
      : (Kb + ((size_t)(bi * cKVH + (hidx - cH)) * cS + sidx) * cHD);
  dst[t] = f2bf(o1);
  dst[t + 64] = f2bf(o2);
}

// --------------------------- V transpose -----------------------------------
__global__ __launch_bounds__(256) void vtrans(const float* __restrict__ QKV,
                                              unsigned short* __restrict__ Vt) {
  __shared__ unsigned short tile[64][72];
  const int t = threadIdx.x;
  const int s0 = blockIdx.x * 64, d0 = blockIdx.y * 64, bi = blockIdx.z;
  {
    const int rr = t >> 2, c0 = (t & 3) * 16;
    const float* src = QKV + (size_t)(bi * cS + s0 + rr) * cNqkv
                       + (cH * cHD + cKVH * cHD) + d0 + c0;
#pragma unroll
    for (int j = 0; j < 16; j += 4) {
      float4 v = *(const float4*)(src + j);
      tile[rr][c0 + j + 0] = f2bf(v.x);
      tile[rr][c0 + j + 1] = f2bf(v.y);
      tile[rr][c0 + j + 2] = f2bf(v.z);
      tile[rr][c0 + j + 3] = f2bf(v.w);
    }
  }
  __syncthreads();
  {
    const int dd = t >> 2, sc0 = (t & 3) * 16;
    const int dglob = d0 + dd;
    const int kh = dglob >> 7, dh = dglob & 127;
    unsigned short* dst = Vt + ((size_t)(bi * cKVH + kh) * cHD + dh) * cS + s0 + sc0;
    ushort8v o0, o1;
#pragma unroll
    for (int j = 0; j < 8; j++) { o0[j] = tile[sc0 + j][dd]; o1[j] = tile[sc0 + 8 + j][dd]; }
    *(ushort8v*)dst = o0;
    *(ushort8v*)(dst + 8) = o1;
  }
}

// --------------------------- flash attention (v4) --------------------------
// Block = 64 q-rows of one (b,h); 4 waves, wave owns 16 q-rows (q-split).
// Bounded scores (RMSNormed q,k) => no running max: P = exp(s*scale), l and O
// are plain sums; l is ONE scalar per lane (its q-row = l16), reduced by two
// shuffles at the end. S^T = K*Q^T so P's C-layout (kv=q*4+rg, qcol=l16) IS
// the K=16 PV A-fragment. K/V staged via global_load_lds into XOR-swizzled
// LDS, double-buffered: DMA(win+1) issued after the single per-iter barrier.
__global__ __launch_bounds__(256, 2) void attn(
    const unsigned short* __restrict__ Qb, const unsigned short* __restrict__ Kb,
    const unsigned short* __restrict__ Vt, unsigned short* __restrict__ AO) {
  __shared__ unsigned short SM[32768];      // 64 KiB: 2 x (Ks 16K + Vs 16K)
  const int tid = threadIdx.x;
  const int lane = tid & 63, wv = tid >> 6;
  const int q = lane >> 4, l16 = lane & 15;
  const int bi = blockIdx.z, h = blockIdx.y;
  const int kh = h >> 1;                    // GQA rep = 2
  const int qt = (int)gridDim.x - 1 - (int)blockIdx.x;  // LPT: heavy first
  const int q0 = qt * 64;
  const int q0w = q0 + wv * 16;             // this wave's first q row

  const unsigned short* Qbase = Qb + ((size_t)(bi * cH + h) * cS + q0w) * cHD;
  const unsigned short* Kbase = Kb + ((size_t)(bi * cKVH + kh) * cS) * cHD;
  const unsigned short* Vbase = Vt + ((size_t)(bi * cKVH + kh) * cHD) * cS;

  // Q as B-operand fragments for S^T = K * Q^T (16 q-rows of this wave)
  short8v qa[4];
#pragma unroll
  for (int c = 0; c < 4; c++)
    qa[c] = *(const short8v*)(Qbase + (size_t)l16 * cHD + c * 32 + q * 8);

  floatx4 oacc[8] = {};       // O[16 q][128 d]: row q*4+rg? no: row=q*4+rg -> q-row, col l16 -> d
  float lp = 0.f;             // partial l for q-row l16

  // staging source offsets (16B units, XOR-swizzled; identical to R3)
  int koff[4], voff[4];
#pragma unroll
  for (int i = 0; i < 4; i++) {
    int s = (wv * 4 + i) * 64 + lane;
    int r = s >> 4, u = (s & 15) ^ (r & 15);
    koff[i] = r * cHD + u * 8;
    int d = s >> 3, uv = (s & 7) ^ (d & 7);
    voff[i] = d * cS + uv * 8;
  }

  auto stage = [&](int win) {
    const int buf = (win & 1) * 16384;
    const int kv0 = win * 64;
    unsigned short* Kdst = SM + buf + (wv * 4) * 512;
    unsigned short* Vdst = SM + buf + 8192 + (wv * 4) * 512;
#pragma unroll
    for (int i = 0; i < 4; i++)
      gl_lds16(Kbase + (size_t)kv0 * cHD + koff[i], Kdst + i * 512);
#pragma unroll
    for (int i = 0; i < 4; i++)
      gl_lds16(Vbase + (size_t)kv0 + voff[i], Vdst + i * 512);
  };

  stage(0);
  for (int win = 0; win <= qt; win++) {
    __syncthreads();                 // drains DMA(win); prev-buf reads done
    if (win < qt) stage(win + 1);    // in flight during compute(win)
    const unsigned short* Ks = SM + (win & 1) * 16384;
    const unsigned short* Vs = Ks + 8192;

    // ---- QK^T -> S^T[64 kv][16 q] for this wave's q slice ----
    floatx4 sres[4] = {};
#pragma unroll
    for (int c = 0; c < 4; c++) {
      short8v kf[4];
#pragma unroll
      for (int ntk = 0; ntk < 4; ntk++)
        kf[ntk] = *(const short8v*)(Ks + (ntk * 16 + l16) * 128 + (((c * 4 + q) ^ l16) * 8));
#pragma unroll
      for (int ntk = 0; ntk < 4; ntk++)
        sres[ntk] = mfma_bf16(kf[ntk], qa[c], sres[ntk]);
    }

    // ---- bounded-score softmax numerator (no max) + causal mask ----
    const bool lastwin = (win == qt);
    short4v pa[4];
#pragma unroll
    for (int ntk = 0; ntk < 4; ntk++) {
#pragma unroll
      for (int rg = 0; rg < 4; rg++) {
        float e = __expf(sres[ntk][rg] * cSCALE);
        if (lastwin && (ntk * 16 + q * 4 + rg > wv * 16 + l16)) e = 0.f;
        lp += e;
        pa[ntk][rg] = (short)f2bf(e);
      }
    }

    // ---- PV: O[16 q][128 d] += P^T-chunk * V-chunk (K=16 each) ----
#pragma unroll
    for (int ntk = 0; ntk < 4; ntk++) {
#pragma unroll
      for (int db = 0; db < 8; db++) {
        short4v vb = *(const short4v*)(Vs + (db * 16 + l16) * 64 +
                       (((ntk * 2 + (q >> 1)) ^ (l16 & 7)) * 8 + (q & 1) * 4));
        oacc[db] = mfma_pv(pa[ntk], vb, oacc[db]);
      }
    }
  }

  // ---- l: sum quads (each quad holds a disjoint kv subset for row l16) ----
  float lf = lp;
  lf += __shfl_xor(lf, 16);
  lf += __shfl_xor(lf, 32);
  // redistribute: lane (q,l16) needs l for q-row q*4+rg (held at lane q*4+rg)
  float li[4];
#pragma unroll
  for (int rg = 0; rg < 4; rg++) li[rg] = 1.0f / __shfl(lf, q * 4 + rg);

#pragma unroll
  for (int rg = 0; rg < 4; rg++) {
    int row = q0w + q * 4 + rg;
    unsigned short* dst = AO + (size_t)(bi * cS + row) * (cH * cHD) + h * cHD;
#pragma unroll
    for (int db = 0; db < 8; db++)
      dst[db * 16 + l16] = f2bf(oacc[db][rg] * li[rg]);
  }
}

// --------------------------- launch ----------------------------------------
extern "C" void kernel_launch(void* const* d_in, const int* in_sizes, int n_in,
                              void* d_out, int out_size, void* d_ws, size_t ws_size,
                              hipStream_t stream) {
  (void)in_sizes; (void)n_in; (void)out_size; (void)ws_size;
  char* ws = (char*)d_ws;
  size_t off = 0;
  auto alloc = [&](size_t bytes) -> char* {
    char* p = ws + off;
    off += (bytes + 255) & ~((size_t)255);
    return p;
  };
  int* flag            = (int*)alloc(256);
  float* cosf_         = (float*)alloc((size_t)cS * cHD * 4);
  float* sinf_         = (float*)alloc((size_t)cS * cHD * 4);
  float* nw            = (float*)alloc(256 * 4);
  float* scat          = (float*)alloc(4096 * 4);
  float* so            = (float*)alloc(2048 * 4);
  unsigned short* xb   = (unsigned short*)alloc((size_t)cM * cD * 2);
  unsigned short* wcat = (unsigned short*)alloc((size_t)cNqkv * cD * 2);
  unsigned short* wob  = (unsigned short*)alloc((size_t)cD * cH * cHD * 2);
  unsigned short* Qb   = (unsigned short*)alloc((size_t)cB * cH * cS * cHD * 2);
  unsigned short* Kb   = (unsigned short*)alloc((size_t)cB * cKVH * cS * cHD * 2);
  unsigned short* Vt   = (unsigned short*)alloc((size_t)cB * cKVH * cHD * cS * 2);
  char* big            = alloc((size_t)cM * cNqkv * 4);
  float* qkvf          = (float*)big;
  unsigned short* AO   = (unsigned short*)big;
  float* of            = (float*)(big + (size_t)cM * cNqkv * 2);

  detect_dtype<<<1, 256, 0, stream>>>((const unsigned*)d_in[0], flag);

  conv_x<<<(cM * cD / 8 + 255) / 256, 256, 0, stream>>>(d_in[0], xb, cM * cD, flag);
  conv_f32<<<(cS * cHD + 255) / 256, 256, 0, stream>>>(d_in[11], cosf_, cS * cHD, flag);
  conv_f32<<<(cS * cHD + 255) / 256, 256, 0, stream>>>(d_in[12], sinf_, cS * cHD, flag);
  conv_f32<<<1, 256, 0, stream>>>(d_in[9], nw, cHD, flag);
  conv_f32<<<1, 256, 0, stream>>>(d_in[10], nw + cHD, cHD, flag);
  conv_f32<<<8, 256, 0, stream>>>(d_in[2], scat, 2048, flag);
  conv_f32<<<4, 256, 0, stream>>>(d_in[4], scat + 2048, 1024, flag);
  conv_f32<<<4, 256, 0, stream>>>(d_in[6], scat + 3072, 1024, flag);
  conv_f32<<<8, 256, 0, stream>>>(d_in[8], so, 2048, flag);
  conv_w<<<(2048 * 2048 / 4 + 255) / 256, 256, 0, stream>>>((const int*)d_in[1], wcat, 2048 * 2048);
  conv_w<<<(1024 * 2048 / 4 + 255) / 256, 256, 0, stream>>>((const int*)d_in[3], wcat + (size_t)2048 * 2048, 1024 * 2048);
  conv_w<<<(1024 * 2048 / 4 + 255) / 256, 256, 0, stream>>>((const int*)d_in[5], wcat + (size_t)3072 * 2048, 1024 * 2048);
  conv_w<<<(2048 * 2048 / 4 + 255) / 256, 256, 0, stream>>>((const int*)d_in[7], wob, 2048 * 2048);

  gemm_bt<<<dim3(cNqkv / 128, cM / 128), 256, 0, stream>>>(xb, wcat, scat, qkvf, cM, cNqkv, cD);
  rmsrope<<<dim3(cM, cH + cKVH), 64, 0, stream>>>(qkvf, cosf_, sinf_, nw, Qb, Kb);
  vtrans<<<dim3(cS / 64, cKVH * cHD / 64, cB), 256, 0, stream>>>(qkvf, Vt);
  attn<<<dim3(cS / 64, cH, cB), 256, 0, stream>>>(Qb, Kb, Vt, AO);
  gemm_bt<<<dim3(cD / 128, cM / 128), 256, 0, stream>>>(AO, wob, so, of, cM, cD, cH * cHD);
  out_conv<<<(cM * cD + 255) / 256, 256, 0, stream>>>(of, d_out, cM * cD, flag);
}